// Round 7
// baseline (6668.951 us; speedup 1.0000x reference)
//
#include <hip/hip_runtime.h>
#include <float.h>

// FPS: N=524288 pts, M=2048 selected (idx[0]=0), out = pos[idxs] (2048x3 f32).
// 256 cooperative blocks x 256 threads (1 block/CU, 1 wave/SIMD, PPT=8).
// R4 topology (validated best: ONLY wave 0 polls fabric; waves 1-3 wait on
// LDS relay; one __syncthreads/iter) + two chain cuts:
//  (a) coords travel IN fabric slots as 4 INDEPENDENT single-word regions
//      (V,X,Y,Z; one 64B line each; all self-tagged; 16 loads per poll
//      attempt, all issued together) -- the detect-side pos[] gather (HBM
//      miss, ~500-700 cyc exposed) is gone. NOT the R1/R3 same-line
//      dependent multi-word pattern; per-line readers stay at 256 (R4 level;
//      R6 showed 1024 readers/line is past the knee).
//  (b) LDS relay: waves 1-3 spin on 3 self-tagged words at once, NO s_sleep
//      (each wave owns its own SIMD -> spinning can't steal wave0 issue),
//      no post-wake reads.
// Publisher coords: leaders park {val, x|y, z} in LDS; after the quad
// reduce, readlane from the winning park; lanes 0-3 store the 4 region
// words in parallel.

#define NPTS     524288
#define MOUT     2048
#define NBLK     256
#define NTHR     256
#define NWAVE    (NTHR / 64)            // 4
#define GTHREADS (NBLK * NTHR)          // 65536
#define PPT      (NPTS / GTHREADS)      // 8
#define SLOT_STRIDE 8                   // u64 per slot -> one 64 B line/slot
#define REGION   (NBLK * SLOT_STRIDE)   // 2048 u64 = 16 KB per region
#define MASK51   ((1ull << 51) - 1)

// V word: [tag:13][fbits:32][idx_inv:19]; X/Y/Z words: [tag:13][0:19][f32:32].
// fbits = IEEE bits of min_d (>=0 so bit order == value order);
// idx_inv = (NPTS-1)-idx: equal values -> smaller idx wins the max
// => first-occurrence tie-break == jnp.argmax (absmax 0.0 R0-R6).
// All 256 block bests are globally distinct (point ownership partitioned),
// so every reduce winner is identified by word equality.
// Slot-reuse safety (parity-2 fabric buffers): publish(i+2) requires this
// block's barrier(i+2) <= all its waves passed iter i+1 <= all blocks
// published(i+1) <= their barriers(i+1) <= their wave0 passed poll(i) --
// no word is re-tagged while any poller still wants tag i. Same chain
// covers the parity-2 LDS relay and single-buffer LDS parks (+ barrier).
// Fabric poison 0xAA.. decodes tag 0x1555, never a real tag (1..2047).

#define DPP_MAX_U64(v, ctrl) do {                                            \
    unsigned _lo = (unsigned)__builtin_amdgcn_update_dpp(                    \
        0, (int)(unsigned)(v), (ctrl), 0xf, 0xf, true);                      \
    unsigned _hi = (unsigned)__builtin_amdgcn_update_dpp(                    \
        0, (int)(unsigned)((v) >> 32), (ctrl), 0xf, 0xf, true);              \
    unsigned long long _s = ((unsigned long long)_hi << 32) | _lo;           \
    if (_s > (v)) (v) = _s;                                                  \
} while (0)

__device__ __forceinline__ unsigned long long wave_max_u64(unsigned long long v)
{
    DPP_MAX_U64(v, 0x111);   // row_shr:1
    DPP_MAX_U64(v, 0x112);   // row_shr:2
    DPP_MAX_U64(v, 0x114);   // row_shr:4
    DPP_MAX_U64(v, 0x118);   // row_shr:8   -> lane15 of each row = row max
    DPP_MAX_U64(v, 0x142);   // row_bcast:15
    DPP_MAX_U64(v, 0x143);   // row_bcast:31 -> lane63 = wave max
    unsigned lo = (unsigned)__builtin_amdgcn_readlane((int)(unsigned)v, 63);
    unsigned hi = (unsigned)__builtin_amdgcn_readlane((int)(unsigned)(v >> 32), 63);
    return ((unsigned long long)hi << 32) | lo;
}

__device__ __forceinline__ unsigned long long quad_max_u64(unsigned long long v)
{
    // values replicated every 4 lanes (v = sred[lane&3]); lane3 = max(v0..v3)
    DPP_MAX_U64(v, 0x111);
    DPP_MAX_U64(v, 0x112);
    unsigned lo = (unsigned)__builtin_amdgcn_readlane((int)(unsigned)v, 3);
    unsigned hi = (unsigned)__builtin_amdgcn_readlane((int)(unsigned)(v >> 32), 3);
    return ((unsigned long long)hi << 32) | lo;
}

__device__ __forceinline__ unsigned readlane_u32(unsigned v, int l)
{
    return (unsigned)__builtin_amdgcn_readlane((int)v, l);
}

__global__ void __launch_bounds__(NTHR, 1) fps_kernel(
    const float* __restrict__ pos, float* __restrict__ out,
    unsigned long long* __restrict__ slots)
{
    const unsigned tid  = threadIdx.x;
    const unsigned lane = tid & 63u;
    const unsigned wav  = tid >> 6;
    const unsigned blk  = blockIdx.x;
    const unsigned g    = blk * NTHR + tid;

    float X[PPT], Y[PPT], Z[PPT], D[PPT];
#pragma unroll
    for (int p = 0; p < PPT; ++p) {
        const unsigned idx = g + (unsigned)p * GTHREADS;
        X[p] = pos[3u * idx + 0];
        Y[p] = pos[3u * idx + 1];
        Z[p] = pos[3u * idx + 2];
        D[p] = FLT_MAX;
    }

    float px = pos[0], py = pos[1], pz = pos[2];
    if (g == 0) { out[0] = px; out[1] = py; out[2] = pz; }

    // LDS parks (leaders -> wave 0): value, packed x|y, z. Single-buffered:
    // ordered by the per-iter barrier + the reuse chain above.
    __shared__ unsigned long long sred[NWAVE], spxy[NWAVE], spz[NWAVE];
    // Parity double-buffered relay (wave 0 -> waves 1-3), self-tagged.
    __shared__ unsigned long long sbc[2][4];   // words 0..2 used
    if (tid < 8) sbc[tid >> 2][tid & 3] = 0ull;   // tag 0 = invalid
    __syncthreads();

    for (int i = 1; i < MOUT; ++i) {
        // ---- distance update + per-thread argmax (exact fp32: no FMA,
        // ---- sum order (dx^2+dy^2)+dz^2; absmax==0 verified R0-R6) ----
        float bv = -1.0f;
        unsigned bi = 0;
#pragma unroll
        for (int p = 0; p < PPT; ++p) {
            float dx = __fsub_rn(X[p], px);
            float dy = __fsub_rn(Y[p], py);
            float dz = __fsub_rn(Z[p], pz);
            float d  = __fadd_rn(__fadd_rn(__fmul_rn(dx, dx), __fmul_rn(dy, dy)),
                                 __fmul_rn(dz, dz));
            float m  = fminf(D[p], d);
            D[p] = m;
            if (m > bv) { bv = m; bi = g + (unsigned)p * GTHREADS; }
        }
        // own-best coords, STATIC indices (validated R3, bit-exact)
        float bx = X[0], by = Y[0], bz = Z[0];
#pragma unroll
        for (int p = 1; p < PPT; ++p) {
            const bool w = (bi == g + (unsigned)p * GTHREADS);
            bx = w ? X[p] : bx;
            by = w ? Y[p] : by;
            bz = w ? Z[p] : bz;
        }
        const unsigned long long mine =
            ((unsigned long long)__float_as_uint(bv) << 19) |
            (unsigned long long)((NPTS - 1u) - bi);

        const unsigned long long tag = (unsigned long long)i;
        const unsigned long long tb  = tag << 51;
        unsigned long long* buf = slots + (unsigned)(i & 1) * (4 * REGION);

        // ---- DPP wave max; winner lane exports coords; leader parks ----
        const unsigned long long wbest = wave_max_u64(mine);
        const int ws = __ffsll(__ballot(mine == wbest)) - 1;   // unique lane
        const unsigned wxb = readlane_u32(__float_as_uint(bx), ws);
        const unsigned wyb = readlane_u32(__float_as_uint(by), ws);
        const unsigned wzb = readlane_u32(__float_as_uint(bz), ws);
        if (lane == 0) {
            sred[wav] = wbest;
            spxy[wav] = ((unsigned long long)wxb << 32) | wyb;
            spz[wav]  = wzb;
        }
        __syncthreads();

        if (wav == 0) {
            // ---- quad reduce + coord pick from parks (loads overlap reduce) ----
            unsigned long long b2  = sred[lane & 3u];
            unsigned long long pxy = spxy[lane & 3u];
            unsigned long long pzw = spz[lane & 3u];
            const unsigned long long bbest = quad_max_u64(b2);
            const int bs = __ffsll(__ballot(b2 == bbest)) - 1;  // park replica
            const unsigned xb = readlane_u32((unsigned)(pxy >> 32), bs);
            const unsigned yb = readlane_u32((unsigned)pxy, bs);
            const unsigned zb = readlane_u32((unsigned)pzw, bs);

            // ---- lanes 0-3 publish the 4 region words in parallel ----
            if (lane < 4u) {
                const unsigned cb = (lane == 1u) ? xb : (lane == 2u) ? yb : zb;
                const unsigned long long w =
                    (lane == 0u) ? (tb | bbest) : (tb | (unsigned long long)cb);
                __hip_atomic_store(&buf[lane * REGION + blk * SLOT_STRIDE], w,
                                   __ATOMIC_RELAXED, __HIP_MEMORY_SCOPE_AGENT);
            }

            // ---- poll: 16 independent single-word slots per lane ----
            unsigned long long* pb = buf + lane * SLOT_STRIDE;
            unsigned long long v0, v1, v2, v3, xw0, xw1, xw2, xw3;
            unsigned long long yw0, yw1, yw2, yw3, zw0, zw1, zw2, zw3;
            do {
                v0  = __hip_atomic_load(pb + 0*REGION + 0*64*SLOT_STRIDE, __ATOMIC_RELAXED, __HIP_MEMORY_SCOPE_AGENT);
                v1  = __hip_atomic_load(pb + 0*REGION + 1*64*SLOT_STRIDE, __ATOMIC_RELAXED, __HIP_MEMORY_SCOPE_AGENT);
                v2  = __hip_atomic_load(pb + 0*REGION + 2*64*SLOT_STRIDE, __ATOMIC_RELAXED, __HIP_MEMORY_SCOPE_AGENT);
                v3  = __hip_atomic_load(pb + 0*REGION + 3*64*SLOT_STRIDE, __ATOMIC_RELAXED, __HIP_MEMORY_SCOPE_AGENT);
                xw0 = __hip_atomic_load(pb + 1*REGION + 0*64*SLOT_STRIDE, __ATOMIC_RELAXED, __HIP_MEMORY_SCOPE_AGENT);
                xw1 = __hip_atomic_load(pb + 1*REGION + 1*64*SLOT_STRIDE, __ATOMIC_RELAXED, __HIP_MEMORY_SCOPE_AGENT);
                xw2 = __hip_atomic_load(pb + 1*REGION + 2*64*SLOT_STRIDE, __ATOMIC_RELAXED, __HIP_MEMORY_SCOPE_AGENT);
                xw3 = __hip_atomic_load(pb + 1*REGION + 3*64*SLOT_STRIDE, __ATOMIC_RELAXED, __HIP_MEMORY_SCOPE_AGENT);
                yw0 = __hip_atomic_load(pb + 2*REGION + 0*64*SLOT_STRIDE, __ATOMIC_RELAXED, __HIP_MEMORY_SCOPE_AGENT);
                yw1 = __hip_atomic_load(pb + 2*REGION + 1*64*SLOT_STRIDE, __ATOMIC_RELAXED, __HIP_MEMORY_SCOPE_AGENT);
                yw2 = __hip_atomic_load(pb + 2*REGION + 2*64*SLOT_STRIDE, __ATOMIC_RELAXED, __HIP_MEMORY_SCOPE_AGENT);
                yw3 = __hip_atomic_load(pb + 2*REGION + 3*64*SLOT_STRIDE, __ATOMIC_RELAXED, __HIP_MEMORY_SCOPE_AGENT);
                zw0 = __hip_atomic_load(pb + 3*REGION + 0*64*SLOT_STRIDE, __ATOMIC_RELAXED, __HIP_MEMORY_SCOPE_AGENT);
                zw1 = __hip_atomic_load(pb + 3*REGION + 1*64*SLOT_STRIDE, __ATOMIC_RELAXED, __HIP_MEMORY_SCOPE_AGENT);
                zw2 = __hip_atomic_load(pb + 3*REGION + 2*64*SLOT_STRIDE, __ATOMIC_RELAXED, __HIP_MEMORY_SCOPE_AGENT);
                zw3 = __hip_atomic_load(pb + 3*REGION + 3*64*SLOT_STRIDE, __ATOMIC_RELAXED, __HIP_MEMORY_SCOPE_AGENT);
                const bool ok =
                    ((v0  >> 51) == tag) & ((v1  >> 51) == tag) &
                    ((v2  >> 51) == tag) & ((v3  >> 51) == tag) &
                    ((xw0 >> 51) == tag) & ((xw1 >> 51) == tag) &
                    ((xw2 >> 51) == tag) & ((xw3 >> 51) == tag) &
                    ((yw0 >> 51) == tag) & ((yw1 >> 51) == tag) &
                    ((yw2 >> 51) == tag) & ((yw3 >> 51) == tag) &
                    ((zw0 >> 51) == tag) & ((zw1 >> 51) == tag) &
                    ((zw2 >> 51) == tag) & ((zw3 >> 51) == tag);
                if (ok) break;
                __builtin_amdgcn_s_sleep(1);
            } while (true);

            // ---- max4 with coord selection (values globally distinct) ----
            unsigned long long c0 = v0 & MASK51, c1 = v1 & MASK51;
            unsigned long long c2 = v2 & MASK51, c3 = v3 & MASK51;
            unsigned long long ca = c0; unsigned xa = (unsigned)xw0,
                ya = (unsigned)yw0, za = (unsigned)zw0;
            if (c1 > ca) { ca = c1; xa = (unsigned)xw1; ya = (unsigned)yw1; za = (unsigned)zw1; }
            unsigned long long cb2 = c2; unsigned xc = (unsigned)xw2,
                yc = (unsigned)yw2, zc = (unsigned)zw2;
            if (c3 > cb2) { cb2 = c3; xc = (unsigned)xw3; yc = (unsigned)yw3; zc = (unsigned)zw3; }
            unsigned long long c = ca; unsigned xs = xa, ys = ya, zs = za;
            if (cb2 > c) { c = cb2; xs = xc; ys = yc; zs = zc; }

            // ---- DPP winner reduce; coords already in registers ----
            const unsigned long long win = wave_max_u64(c);
            const int src = __ffsll(__ballot(c == win)) - 1;  // unique lane
            px = __uint_as_float(readlane_u32(xs, src));
            py = __uint_as_float(readlane_u32(ys, src));
            pz = __uint_as_float(readlane_u32(zs, src));

            // ---- LDS relay to waves 1-3: 3 self-tagged words in parallel ----
            if (lane < 3u) {
                const unsigned cv = (lane == 0u) ? __float_as_uint(px)
                                  : (lane == 1u) ? __float_as_uint(py)
                                                 : __float_as_uint(pz);
                __hip_atomic_store(&sbc[i & 1][lane],
                                   tb | (unsigned long long)cv,
                                   __ATOMIC_RELAXED, __HIP_MEMORY_SCOPE_WORKGROUP);
            }

            if (blk == 0 && lane == 0) {
                out[3 * i + 0] = px; out[3 * i + 1] = py; out[3 * i + 2] = pz;
            }
        } else {
            // ---- waves 1-3: spin on all 3 relay words, NO sleep (own SIMD;
            // ---- LDS spin is free and wakes at store+load latency) ----
            unsigned long long xw, yw, zw;
            do {
                xw = __hip_atomic_load(&sbc[i & 1][0],
                                       __ATOMIC_RELAXED, __HIP_MEMORY_SCOPE_WORKGROUP);
                yw = __hip_atomic_load(&sbc[i & 1][1],
                                       __ATOMIC_RELAXED, __HIP_MEMORY_SCOPE_WORKGROUP);
                zw = __hip_atomic_load(&sbc[i & 1][2],
                                       __ATOMIC_RELAXED, __HIP_MEMORY_SCOPE_WORKGROUP);
            } while (!(((xw >> 51) == tag) & ((yw >> 51) == tag) &
                       ((zw >> 51) == tag)));
            px = __uint_as_float((unsigned)xw);
            py = __uint_as_float((unsigned)yw);
            pz = __uint_as_float((unsigned)zw);
        }
        // no trailing sync: next iteration's pre-publish barrier + monotone
        // tags + parity-2 buffers make all reuse safe (chain at top).
    }
}

extern "C" void kernel_launch(void* const* d_in, const int* in_sizes, int n_in,
                              void* d_out, int out_size, void* d_ws, size_t ws_size,
                              hipStream_t stream) {
    const float* pos = (const float*)d_in[0];
    float* out = (float*)d_out;
    unsigned long long* slots = (unsigned long long*)d_ws;
    // Workspace: 2 parities x 4 regions x 256 slots x 64 B = 128 KB.
    // No memset: 0xAA poison decodes to tag 0x1555, never a real tag
    // (1..2047); monotone tags + 2-buffer rotation make stale words harmless.

    void* args[] = { (void*)&pos, (void*)&out, (void*)&slots };
    hipLaunchCooperativeKernel((void*)fps_kernel, dim3(NBLK), dim3(NTHR),
                               args, 0, stream);
}

// Round 8
// 5092.475 us; speedup vs baseline: 1.3096x; 1.3096x over previous
//
#include <hip/hip_runtime.h>
#include <float.h>

// FPS: N=524288 pts, M=2048 selected (idx[0]=0), out = pos[idxs] (2048x3 f32).
// 256 cooperative blocks x 256 threads (1 block/CU, 1 wave/SIMD, PPT=8).
// R4 topology EXACTLY (validated best 4614us: ONLY wave 0 polls fabric,
// 4 value-only slot loads/attempt, one __syncthreads/iter, LDS relay to
// waves 1-3) + two off-fabric chain trims:
//  (a) relay: lanes 0-2 store 3 self-tagged words in parallel; waves 1-3
//      relaxed no-sleep 3-word tag-spin (own SIMD -> spinning is free; no
//      acquire, no sleep quantization).
//  (b) gather: issue ALL 4 candidates' coord loads at poll exit; max4
//      tracks slot index j; DPP winner reduce runs load-independent; coord
//      select by j happens AFTER the reduce so vmcnt hides under it.
// Contention law (R4 vs R6/R7): total agent-load rate ~1024/round is fine,
// ~4096/round regresses 40% -- this kernel keeps R4's exact rate.

#define NPTS     524288
#define MOUT     2048
#define NBLK     256
#define NTHR     256
#define NWAVE    (NTHR / 64)            // 4
#define GTHREADS (NBLK * NTHR)          // 65536
#define PPT      (NPTS / GTHREADS)      // 8
#define SLOT_STRIDE 8                   // u64 per slot -> one 64 B line/slot
#define MASK51   ((1ull << 51) - 1)

// slot word: [tag:13][fbits:32][idx_inv:19]
// fbits = IEEE bits of min_d (>=0 so bit order == value order)
// idx_inv = (NPTS-1)-idx: equal values -> smaller idx wins the max
// => first-occurrence tie-break == jnp.argmax (absmax 0.0 R0-R7).
// All 256 block bests are globally distinct (point ownership partitioned),
// so every reduce winner is identified by word equality.
// Slot-reuse safety (parity-2 fabric buffers): publish(i+2) requires this
// block's barrier(i+2) <= all its waves passed iter i+1 <= all blocks
// published(i+1) <= their barriers(i+1) <= their wave0 passed poll(i) --
// no word is re-tagged while any poller still wants tag i. Same chain
// covers the parity-2 LDS relay and single-buffer LDS parks (+ barrier).
// Fabric poison 0xAA.. decodes tag 0x1555, never a real tag (1..2047).

#define DPP_MAX_U64(v, ctrl) do {                                            \
    unsigned _lo = (unsigned)__builtin_amdgcn_update_dpp(                    \
        0, (int)(unsigned)(v), (ctrl), 0xf, 0xf, true);                      \
    unsigned _hi = (unsigned)__builtin_amdgcn_update_dpp(                    \
        0, (int)(unsigned)((v) >> 32), (ctrl), 0xf, 0xf, true);              \
    unsigned long long _s = ((unsigned long long)_hi << 32) | _lo;           \
    if (_s > (v)) (v) = _s;                                                  \
} while (0)

__device__ __forceinline__ unsigned long long wave_max_u64(unsigned long long v)
{
    DPP_MAX_U64(v, 0x111);   // row_shr:1
    DPP_MAX_U64(v, 0x112);   // row_shr:2
    DPP_MAX_U64(v, 0x114);   // row_shr:4
    DPP_MAX_U64(v, 0x118);   // row_shr:8   -> lane15 of each row = row max
    DPP_MAX_U64(v, 0x142);   // row_bcast:15
    DPP_MAX_U64(v, 0x143);   // row_bcast:31 -> lane63 = wave max
    unsigned lo = (unsigned)__builtin_amdgcn_readlane((int)(unsigned)v, 63);
    unsigned hi = (unsigned)__builtin_amdgcn_readlane((int)(unsigned)(v >> 32), 63);
    return ((unsigned long long)hi << 32) | lo;
}

__device__ __forceinline__ unsigned long long quad_max_u64(unsigned long long v)
{
    // values replicated every 4 lanes (v = sred[lane&3]); lane3 = max(v0..v3)
    DPP_MAX_U64(v, 0x111);
    DPP_MAX_U64(v, 0x112);
    unsigned lo = (unsigned)__builtin_amdgcn_readlane((int)(unsigned)v, 3);
    unsigned hi = (unsigned)__builtin_amdgcn_readlane((int)(unsigned)(v >> 32), 3);
    return ((unsigned long long)hi << 32) | lo;
}

__device__ __forceinline__ float readlane_f(float v, int l)
{
    return __uint_as_float(
        (unsigned)__builtin_amdgcn_readlane((int)__float_as_uint(v), l));
}

__global__ void __launch_bounds__(NTHR, 1) fps_kernel(
    const float* __restrict__ pos, float* __restrict__ out,
    unsigned long long* __restrict__ slots)
{
    const unsigned tid  = threadIdx.x;
    const unsigned lane = tid & 63u;
    const unsigned wav  = tid >> 6;
    const unsigned blk  = blockIdx.x;
    const unsigned g    = blk * NTHR + tid;

    float X[PPT], Y[PPT], Z[PPT], D[PPT];
#pragma unroll
    for (int p = 0; p < PPT; ++p) {
        const unsigned idx = g + (unsigned)p * GTHREADS;
        X[p] = pos[3u * idx + 0];
        Y[p] = pos[3u * idx + 1];
        Z[p] = pos[3u * idx + 2];
        D[p] = FLT_MAX;
    }

    float px = pos[0], py = pos[1], pz = pos[2];
    if (g == 0) { out[0] = px; out[1] = py; out[2] = pz; }

    // Wave bests (leaders -> wave 0). Single buffer safe: wave w parks i+1
    // only after detecting i via the relay, which wave0 writes only after it
    // already consumed the parks for i (+ the per-iter barrier orders reads).
    __shared__ unsigned long long sred[NWAVE];
    // Parity double-buffered relay (wave 0 -> waves 1-3), self-tagged words.
    __shared__ unsigned long long sbc[2][4];   // words 0..2 used
    if (tid < 8) sbc[tid >> 2][tid & 3] = 0ull;   // tag 0 = invalid
    __syncthreads();

    for (int i = 1; i < MOUT; ++i) {
        // ---- distance update + per-thread argmax (exact fp32: no FMA,
        // ---- sum order (dx^2+dy^2)+dz^2; absmax==0 verified R0-R7) ----
        float bv = -1.0f;
        unsigned bi = 0;
#pragma unroll
        for (int p = 0; p < PPT; ++p) {
            float dx = __fsub_rn(X[p], px);
            float dy = __fsub_rn(Y[p], py);
            float dz = __fsub_rn(Z[p], pz);
            float d  = __fadd_rn(__fadd_rn(__fmul_rn(dx, dx), __fmul_rn(dy, dy)),
                                 __fmul_rn(dz, dz));
            float m  = fminf(D[p], d);
            D[p] = m;
            if (m > bv) { bv = m; bi = g + (unsigned)p * GTHREADS; }
        }
        const unsigned long long mine =
            ((unsigned long long)__float_as_uint(bv) << 19) |
            (unsigned long long)((NPTS - 1u) - bi);

        const unsigned long long tag = (unsigned long long)i;
        const unsigned long long tb  = tag << 51;
        unsigned long long* buf = slots + (unsigned)(i & 1) * (NBLK * SLOT_STRIDE);

        // ---- DPP wave max; leader parks it; barrier orders parks vs read ----
        const unsigned long long wbest = wave_max_u64(mine);
        if (lane == 0) sred[wav] = wbest;
        __syncthreads();

        if (wav == 0) {
            // ---- 4-value DPP reduce -> block best; lane0 publishes ----
            unsigned long long b2 = sred[lane & (NWAVE - 1u)];
            const unsigned long long bbest = quad_max_u64(b2);
            if (lane == 0) {
                __hip_atomic_store(&buf[blk * SLOT_STRIDE], tb | bbest,
                                   __ATOMIC_RELAXED, __HIP_MEMORY_SCOPE_AGENT);
            }

            // ---- poll 256 slots: 4 independent single-word slots/lane ----
            unsigned long long* base = buf + lane * SLOT_STRIDE;
            unsigned long long s0, s1, s2, s3;
            do {
                s0 = __hip_atomic_load(base + 0 * 64 * SLOT_STRIDE,
                                       __ATOMIC_RELAXED, __HIP_MEMORY_SCOPE_AGENT);
                s1 = __hip_atomic_load(base + 1 * 64 * SLOT_STRIDE,
                                       __ATOMIC_RELAXED, __HIP_MEMORY_SCOPE_AGENT);
                s2 = __hip_atomic_load(base + 2 * 64 * SLOT_STRIDE,
                                       __ATOMIC_RELAXED, __HIP_MEMORY_SCOPE_AGENT);
                s3 = __hip_atomic_load(base + 3 * 64 * SLOT_STRIDE,
                                       __ATOMIC_RELAXED, __HIP_MEMORY_SCOPE_AGENT);
                if (((s0 >> 51) == tag) & ((s1 >> 51) == tag) &
                    ((s2 >> 51) == tag) & ((s3 >> 51) == tag)) break;
                __builtin_amdgcn_s_sleep(1);
            } while (true);

            // ---- issue ALL 4 candidates' gathers NOW (cached loads, fly
            // ---- under max4 + winner reduce; pos is L2/L3-resident) ----
            const unsigned q0 = 0x7FFFFu - (unsigned)(s0 & 0x7FFFFull);
            const unsigned q1 = 0x7FFFFu - (unsigned)(s1 & 0x7FFFFull);
            const unsigned q2 = 0x7FFFFu - (unsigned)(s2 & 0x7FFFFull);
            const unsigned q3 = 0x7FFFFu - (unsigned)(s3 & 0x7FFFFull);
            const float cx0 = pos[3u*q0+0], cy0 = pos[3u*q0+1], cz0 = pos[3u*q0+2];
            const float cx1 = pos[3u*q1+0], cy1 = pos[3u*q1+1], cz1 = pos[3u*q1+2];
            const float cx2 = pos[3u*q2+0], cy2 = pos[3u*q2+1], cz2 = pos[3u*q2+2];
            const float cx3 = pos[3u*q3+0], cy3 = pos[3u*q3+1], cz3 = pos[3u*q3+2];

            // ---- max4 tracking slot index j (values globally distinct) ----
            unsigned long long c0 = s0 & MASK51, c1 = s1 & MASK51;
            unsigned long long c2 = s2 & MASK51, c3 = s3 & MASK51;
            unsigned long long ca = c0; unsigned ja = 0u;
            if (c1 > ca) { ca = c1; ja = 1u; }
            unsigned long long cb = c2; unsigned jb = 2u;
            if (c3 > cb) { cb = c3; jb = 3u; }
            unsigned long long c = ca; unsigned j = ja;
            if (cb > c) { c = cb; j = jb; }

            // ---- DPP winner reduce (register-only; loads still flying) ----
            const unsigned long long win = wave_max_u64(c);
            const int src = __ffsll(__ballot(c == win)) - 1;  // unique lane

            // ---- coord select by j (vmcnt waits land here, post-reduce) ----
            const float fx = (j == 0u) ? cx0 : (j == 1u) ? cx1
                           : (j == 2u) ? cx2 : cx3;
            const float fy = (j == 0u) ? cy0 : (j == 1u) ? cy1
                           : (j == 2u) ? cy2 : cy3;
            const float fz = (j == 0u) ? cz0 : (j == 1u) ? cz1
                           : (j == 2u) ? cz2 : cz3;
            px = readlane_f(fx, src);
            py = readlane_f(fy, src);
            pz = readlane_f(fz, src);

            // ---- LDS relay: lanes 0-2 store 3 self-tagged words in parallel ----
            if (lane < 3u) {
                const unsigned cv = (lane == 0u) ? __float_as_uint(px)
                                  : (lane == 1u) ? __float_as_uint(py)
                                                 : __float_as_uint(pz);
                __hip_atomic_store(&sbc[i & 1][lane],
                                   tb | (unsigned long long)cv,
                                   __ATOMIC_RELAXED, __HIP_MEMORY_SCOPE_WORKGROUP);
            }

            if (blk == 0 && lane == 0) {
                out[3 * i + 0] = px; out[3 * i + 1] = py; out[3 * i + 2] = pz;
            }
        } else {
            // ---- waves 1-3: relaxed no-sleep tag-spin on the 3 relay words
            // ---- (own SIMD -> free; each word self-tagged -> no ordering) ----
            unsigned long long xw, yw, zw;
            do {
                xw = __hip_atomic_load(&sbc[i & 1][0],
                                       __ATOMIC_RELAXED, __HIP_MEMORY_SCOPE_WORKGROUP);
                yw = __hip_atomic_load(&sbc[i & 1][1],
                                       __ATOMIC_RELAXED, __HIP_MEMORY_SCOPE_WORKGROUP);
                zw = __hip_atomic_load(&sbc[i & 1][2],
                                       __ATOMIC_RELAXED, __HIP_MEMORY_SCOPE_WORKGROUP);
            } while (!(((xw >> 51) == tag) & ((yw >> 51) == tag) &
                       ((zw >> 51) == tag)));
            px = __uint_as_float((unsigned)xw);
            py = __uint_as_float((unsigned)yw);
            pz = __uint_as_float((unsigned)zw);
        }
        // no trailing sync: next iteration's pre-publish barrier + monotone
        // tags + parity-2 buffers make all reuse safe (chain at top).
    }
}

extern "C" void kernel_launch(void* const* d_in, const int* in_sizes, int n_in,
                              void* d_out, int out_size, void* d_ws, size_t ws_size,
                              hipStream_t stream) {
    const float* pos = (const float*)d_in[0];
    float* out = (float*)d_out;
    unsigned long long* slots = (unsigned long long*)d_ws;  // 2 x 256 x 64B = 32 KB
    // No memset: 0xAA poison decodes to tag 0x1555, never a real tag (1..2047);
    // monotone tags + 2-buffer rotation make stale words harmless.

    void* args[] = { (void*)&pos, (void*)&out, (void*)&slots };
    hipLaunchCooperativeKernel((void*)fps_kernel, dim3(NBLK), dim3(NTHR),
                               args, 0, stream);
}

// Round 9
// 4571.560 us; speedup vs baseline: 1.4588x; 1.1139x over previous
//
#include <hip/hip_runtime.h>
#include <float.h>

// FPS: N=524288 pts, M=2048 selected (idx[0]=0), out = pos[idxs] (2048x3 f32).
// 256 cooperative blocks x 256 threads (1 block/CU, 1 wave/SIMD, PPT=8).
// EXACT R4 structure (validated best 4614us: ONLY wave 0 polls fabric,
// 4 value-only slot loads/attempt + s_sleep(1), one __syncthreads/iter,
// lane-local-max coord prefetch overlapping the winner reduce) with ONE
// change vs R4 (clean bisect of R8's a+b bundle):
//  (a) LDS relay: lanes 0-2 store 3 self-tagged words in parallel (was:
//      lane0 serial y,z then x-release); waves 1-3 relaxed NO-SLEEP tag-spin
//      on all 3 words (own SIMD -> spin is free; no acquire, no s_sleep
//      wake quantization).
// R8's (b) (gather all 4 candidates) is REVERTED: 4x L3 gather lines
// queued behind the agent-poll storm cost ~230 cyc/iter.
// Contention law (R4 vs R6/R7): ~1024 agent loads/round fine, ~4096 bad.

#define NPTS     524288
#define MOUT     2048
#define NBLK     256
#define NTHR     256
#define NWAVE    (NTHR / 64)            // 4
#define GTHREADS (NBLK * NTHR)          // 65536
#define PPT      (NPTS / GTHREADS)      // 8
#define SLOT_STRIDE 8                   // u64 per slot -> one 64 B line/slot
#define MASK51   ((1ull << 51) - 1)

// slot word: [tag:13][fbits:32][idx_inv:19]
// fbits = IEEE bits of min_d (>=0 so bit order == value order)
// idx_inv = (NPTS-1)-idx: equal values -> smaller idx wins the max
// => first-occurrence tie-break == jnp.argmax (absmax 0.0 R0-R8).
// (32-bit value-only reduces were considered and rejected: lane-order
// tie-break != smallest point idx, since idx = g + p*GTHREADS is p-major.)
// All 256 block bests are globally distinct (point ownership partitioned),
// so every reduce winner is identified by word equality.
// Slot-reuse safety (parity-2 fabric buffers): publish(i+2) requires this
// block's barrier(i+2) <= all its waves passed iter i+1 <= all blocks
// published(i+1) <= their barriers(i+1) <= their wave0 passed poll(i) --
// no word is re-tagged while any poller still wants tag i. Same chain
// covers the parity-2 LDS relay and single-buffer LDS parks (+ barrier).
// Fabric poison 0xAA.. decodes tag 0x1555, never a real tag (1..2047).

#define DPP_MAX_U64(v, ctrl) do {                                            \
    unsigned _lo = (unsigned)__builtin_amdgcn_update_dpp(                    \
        0, (int)(unsigned)(v), (ctrl), 0xf, 0xf, true);                      \
    unsigned _hi = (unsigned)__builtin_amdgcn_update_dpp(                    \
        0, (int)(unsigned)((v) >> 32), (ctrl), 0xf, 0xf, true);              \
    unsigned long long _s = ((unsigned long long)_hi << 32) | _lo;           \
    if (_s > (v)) (v) = _s;                                                  \
} while (0)

__device__ __forceinline__ unsigned long long wave_max_u64(unsigned long long v)
{
    DPP_MAX_U64(v, 0x111);   // row_shr:1
    DPP_MAX_U64(v, 0x112);   // row_shr:2
    DPP_MAX_U64(v, 0x114);   // row_shr:4
    DPP_MAX_U64(v, 0x118);   // row_shr:8   -> lane15 of each row = row max
    DPP_MAX_U64(v, 0x142);   // row_bcast:15
    DPP_MAX_U64(v, 0x143);   // row_bcast:31 -> lane63 = wave max
    unsigned lo = (unsigned)__builtin_amdgcn_readlane((int)(unsigned)v, 63);
    unsigned hi = (unsigned)__builtin_amdgcn_readlane((int)(unsigned)(v >> 32), 63);
    return ((unsigned long long)hi << 32) | lo;
}

__device__ __forceinline__ unsigned long long quad_max_u64(unsigned long long v)
{
    // values replicated every 4 lanes (v = sred[lane&3]); lane3 = max(v0..v3)
    DPP_MAX_U64(v, 0x111);
    DPP_MAX_U64(v, 0x112);
    unsigned lo = (unsigned)__builtin_amdgcn_readlane((int)(unsigned)v, 3);
    unsigned hi = (unsigned)__builtin_amdgcn_readlane((int)(unsigned)(v >> 32), 3);
    return ((unsigned long long)hi << 32) | lo;
}

__device__ __forceinline__ float readlane_f(float v, int l)
{
    return __uint_as_float(
        (unsigned)__builtin_amdgcn_readlane((int)__float_as_uint(v), l));
}

__global__ void __launch_bounds__(NTHR, 1) fps_kernel(
    const float* __restrict__ pos, float* __restrict__ out,
    unsigned long long* __restrict__ slots)
{
    const unsigned tid  = threadIdx.x;
    const unsigned lane = tid & 63u;
    const unsigned wav  = tid >> 6;
    const unsigned blk  = blockIdx.x;
    const unsigned g    = blk * NTHR + tid;

    float X[PPT], Y[PPT], Z[PPT], D[PPT];
#pragma unroll
    for (int p = 0; p < PPT; ++p) {
        const unsigned idx = g + (unsigned)p * GTHREADS;
        X[p] = pos[3u * idx + 0];
        Y[p] = pos[3u * idx + 1];
        Z[p] = pos[3u * idx + 2];
        D[p] = FLT_MAX;
    }

    float px = pos[0], py = pos[1], pz = pos[2];
    if (g == 0) { out[0] = px; out[1] = py; out[2] = pz; }

    // Wave bests (leaders -> wave 0). Single buffer safe: wave w parks i+1
    // only after detecting i via the relay, which wave0 writes only after it
    // already consumed the parks for i (+ the per-iter barrier orders reads).
    __shared__ unsigned long long sred[NWAVE];
    // Parity double-buffered relay (wave 0 -> waves 1-3), self-tagged words.
    __shared__ unsigned long long sbc[2][4];   // words 0..2 used
    if (tid < 8) sbc[tid >> 2][tid & 3] = 0ull;   // tag 0 = invalid
    __syncthreads();

    for (int i = 1; i < MOUT; ++i) {
        // ---- distance update + per-thread argmax (exact fp32: no FMA,
        // ---- sum order (dx^2+dy^2)+dz^2; absmax==0 verified R0-R8) ----
        float bv = -1.0f;
        unsigned bi = 0;
#pragma unroll
        for (int p = 0; p < PPT; ++p) {
            float dx = __fsub_rn(X[p], px);
            float dy = __fsub_rn(Y[p], py);
            float dz = __fsub_rn(Z[p], pz);
            float d  = __fadd_rn(__fadd_rn(__fmul_rn(dx, dx), __fmul_rn(dy, dy)),
                                 __fmul_rn(dz, dz));
            float m  = fminf(D[p], d);
            D[p] = m;
            if (m > bv) { bv = m; bi = g + (unsigned)p * GTHREADS; }
        }
        const unsigned long long mine =
            ((unsigned long long)__float_as_uint(bv) << 19) |
            (unsigned long long)((NPTS - 1u) - bi);

        const unsigned long long tag = (unsigned long long)i;
        const unsigned long long tb  = tag << 51;
        unsigned long long* buf = slots + (unsigned)(i & 1) * (NBLK * SLOT_STRIDE);

        // ---- DPP wave max; leader parks it; barrier orders parks vs read ----
        const unsigned long long wbest = wave_max_u64(mine);
        if (lane == 0) sred[wav] = wbest;
        __syncthreads();

        if (wav == 0) {
            // ---- 4-value DPP reduce -> block best; lane0 publishes ----
            unsigned long long b2 = sred[lane & (NWAVE - 1u)];
            const unsigned long long bbest = quad_max_u64(b2);
            if (lane == 0) {
                __hip_atomic_store(&buf[blk * SLOT_STRIDE], tb | bbest,
                                   __ATOMIC_RELAXED, __HIP_MEMORY_SCOPE_AGENT);
            }

            // ---- poll 256 slots: 4 independent single-word slots/lane ----
            unsigned long long* base = buf + lane * SLOT_STRIDE;
            unsigned long long s0, s1, s2, s3;
            do {
                s0 = __hip_atomic_load(base + 0 * 64 * SLOT_STRIDE,
                                       __ATOMIC_RELAXED, __HIP_MEMORY_SCOPE_AGENT);
                s1 = __hip_atomic_load(base + 1 * 64 * SLOT_STRIDE,
                                       __ATOMIC_RELAXED, __HIP_MEMORY_SCOPE_AGENT);
                s2 = __hip_atomic_load(base + 2 * 64 * SLOT_STRIDE,
                                       __ATOMIC_RELAXED, __HIP_MEMORY_SCOPE_AGENT);
                s3 = __hip_atomic_load(base + 3 * 64 * SLOT_STRIDE,
                                       __ATOMIC_RELAXED, __HIP_MEMORY_SCOPE_AGENT);
                if (((s0 >> 51) == tag) & ((s1 >> 51) == tag) &
                    ((s2 >> 51) == tag) & ((s3 >> 51) == tag)) break;
                __builtin_amdgcn_s_sleep(1);
            } while (true);

            // ---- local max of 4 (values globally distinct) ----
            unsigned long long c0 = s0 & MASK51, c1 = s1 & MASK51;
            unsigned long long c2 = s2 & MASK51, c3 = s3 & MASK51;
            unsigned long long ca = (c0 > c1) ? c0 : c1;
            unsigned long long cb = (c2 > c3) ? c2 : c3;
            unsigned long long c  = (ca > cb) ? ca : cb;

            // prefetch this lane's candidate coords; loads fly during reduce
            const unsigned cidx = (NPTS - 1u) - (unsigned)(c & 0x7FFFFull);
            const float cx = pos[3u * cidx + 0];
            const float cy = pos[3u * cidx + 1];
            const float cz = pos[3u * cidx + 2];

            // ---- DPP winner reduce over 64 lane-local maxes; readlane coords ----
            const unsigned long long win = wave_max_u64(c);
            const int src = __ffsll(__ballot(c == win)) - 1;  // unique lane
            px = readlane_f(cx, src);
            py = readlane_f(cy, src);
            pz = readlane_f(cz, src);

            // ---- LDS relay: lanes 0-2 store 3 self-tagged words in parallel ----
            if (lane < 3u) {
                const unsigned cv = (lane == 0u) ? __float_as_uint(px)
                                  : (lane == 1u) ? __float_as_uint(py)
                                                 : __float_as_uint(pz);
                __hip_atomic_store(&sbc[i & 1][lane],
                                   tb | (unsigned long long)cv,
                                   __ATOMIC_RELAXED, __HIP_MEMORY_SCOPE_WORKGROUP);
            }

            if (blk == 0 && lane == 0) {
                out[3 * i + 0] = px; out[3 * i + 1] = py; out[3 * i + 2] = pz;
            }
        } else {
            // ---- waves 1-3: relaxed no-sleep tag-spin on the 3 relay words
            // ---- (own SIMD -> free; each word self-tagged -> no ordering) ----
            unsigned long long xw, yw, zw;
            do {
                xw = __hip_atomic_load(&sbc[i & 1][0],
                                       __ATOMIC_RELAXED, __HIP_MEMORY_SCOPE_WORKGROUP);
                yw = __hip_atomic_load(&sbc[i & 1][1],
                                       __ATOMIC_RELAXED, __HIP_MEMORY_SCOPE_WORKGROUP);
                zw = __hip_atomic_load(&sbc[i & 1][2],
                                       __ATOMIC_RELAXED, __HIP_MEMORY_SCOPE_WORKGROUP);
            } while (!(((xw >> 51) == tag) & ((yw >> 51) == tag) &
                       ((zw >> 51) == tag)));
            px = __uint_as_float((unsigned)xw);
            py = __uint_as_float((unsigned)yw);
            pz = __uint_as_float((unsigned)zw);
        }
        // no trailing sync: next iteration's pre-publish barrier + monotone
        // tags + parity-2 buffers make all reuse safe (chain at top).
    }
}

extern "C" void kernel_launch(void* const* d_in, const int* in_sizes, int n_in,
                              void* d_out, int out_size, void* d_ws, size_t ws_size,
                              hipStream_t stream) {
    const float* pos = (const float*)d_in[0];
    float* out = (float*)d_out;
    unsigned long long* slots = (unsigned long long*)d_ws;  // 2 x 256 x 64B = 32 KB
    // No memset: 0xAA poison decodes to tag 0x1555, never a real tag (1..2047);
    // monotone tags + 2-buffer rotation make stale words harmless.

    void* args[] = { (void*)&pos, (void*)&out, (void*)&slots };
    hipLaunchCooperativeKernel((void*)fps_kernel, dim3(NBLK), dim3(NTHR),
                               args, 0, stream);
}